// Round 9
// baseline (1018.730 us; speedup 1.0000x reference)
//
#include <hip/hip_runtime.h>
#include <cstdint>
#include <cstddef>

#define HID    256
#define NROW   1024          // 4*HID gate rows
#define KSTEPS 7
#define ZM     64
#define BATCH  32768
#define WMSZ   (BATCH * ZM)  // floats per (which,m) output slab
#define NBLKS  1792          // 14 slabs x 128 chunks; 66 lowest blocks double as producers

typedef float f32x4 __attribute__((ext_vector_type(4)));

// ---- ws layout (float offsets); first 256 B zeroed by hipMemsetAsync ----
#define WS_FLAGS 0                   // uint flags[14] : tab row (which,m) ready
#define WS_GCNT  32                  // uint gcnt[6]   : gate blocks done for step s
#define WS_GATES 64                  // 6 x 1024 pre-activation gates
#define WS_TAB   (64 + 6 * NROW)     // 896 projection table [which][m][j]

__device__ __forceinline__ float sigf(float x)       { return 1.0f / (1.0f + __expf(-x)); }
__device__ __forceinline__ float tanhf_fast(float x) { return 1.0f - 2.0f / (__expf(2.0f * x) + 1.0f); }
__device__ __forceinline__ float dot4(f32x4 a, f32x4 b) {
    return a.x * b.x + a.y * b.y + a.z * b.z + a.w * b.w;
}

__global__ __launch_bounds__(256, 8) void mega_kernel(
    const float* __restrict__ zm1,
    const float* __restrict__ Wih, const float* __restrict__ Whh,
    const float* __restrict__ bih, const float* __restrict__ bhh,
    const float* __restrict__ Wloc, const float* __restrict__ bloc,
    const float* __restrict__ Wsc,  const float* __restrict__ bsc,
    float* __restrict__ ws, f32x4* __restrict__ out)
{
    const int t = threadIdx.x, b = blockIdx.x;
    unsigned* flags = (unsigned*)ws + WS_FLAGS;
    unsigned* gcnt  = (unsigned*)ws + WS_GCNT;
    float* gates = ws + WS_GATES;
    float* tab   = ws + WS_TAB;

    __shared__ float hsh[HID];

    // ================= producer phase (blocks 0..65 only) =================
    if (b < 64) {
        // ---- gate-matvec producer: 16 rows, 16 threads/row, 16 cols/thread ----
        float c = 0.f;                           // c[t] chain, redundant per block
        const int row = b * 16 + (t >> 4);
        const int cb  = (t & 15) * 4;            // f32x4 column base
        const f32x4* wi = (const f32x4*)(Wih + (size_t)row * HID);
        const f32x4* wh = (const f32x4*)(Whh + (size_t)row * HID);
        const float bias = bih[row] + bhh[row];
        #pragma unroll 1
        for (int s = 0; s <= 5; ++s) {
            float h;
            if (s == 0) {
                h = zm1[t];                      // h0==0: step 0 uses Wih.zm1 only
            } else {
                if (t == 0) {
                    while (__hip_atomic_load(&gcnt[s - 1], __ATOMIC_ACQUIRE, __HIP_MEMORY_SCOPE_AGENT) < 64u)
                        __builtin_amdgcn_s_sleep(1);
                }
                __syncthreads();
                const float* gp = gates + (size_t)(s - 1) * NROW;
                float gi = gp[t], gf = gp[HID + t], gg = gp[2 * HID + t], go = gp[3 * HID + t];
                c = sigf(gf) * c + sigf(gi) * tanhf_fast(gg);
                h = sigf(go) * tanhf_fast(c);
            }
            __syncthreads();
            hsh[t] = h;
            __syncthreads();
            const f32x4* h4 = (const f32x4*)hsh;
            float part = 0.f;
            #pragma unroll
            for (int kk = 0; kk < 4; ++kk) {
                f32x4 hv = h4[cb + kk];
                part += dot4(wi[cb + kk], hv);
                if (s > 0) part += dot4(wh[cb + kk], hv);
            }
            part += __shfl_xor(part, 1);
            part += __shfl_xor(part, 2);
            part += __shfl_xor(part, 4);
            part += __shfl_xor(part, 8);
            if ((t & 15) == 0) gates[(size_t)s * NROW + row] = part + bias;
            __threadfence();                     // publish gates before count bump
            __syncthreads();
            if (t == 0)
                __hip_atomic_fetch_add(&gcnt[s], 1u, __ATOMIC_RELEASE, __HIP_MEMORY_SCOPE_AGENT);
        }
    } else if (b < 66) {
        // ---- projection producer: b=64 -> loc, b=65 -> scale ----
        float c = 0.f;
        const int which = b - 64;
        const float* W  = which ? Wsc : Wloc;
        const float* bv = which ? bsc : bloc;
        const int j = t >> 2, q = t & 3;
        const f32x4* w4 = (const f32x4*)(W + (size_t)j * HID);
        const float bj = bv[j];
        #pragma unroll 1
        for (int m = 0; m <= 6; ++m) {
            float h;
            if (m == 0) {
                h = zm1[t];
            } else {
                if (t == 0) {
                    while (__hip_atomic_load(&gcnt[m - 1], __ATOMIC_ACQUIRE, __HIP_MEMORY_SCOPE_AGENT) < 64u)
                        __builtin_amdgcn_s_sleep(1);
                }
                __syncthreads();
                const float* gp = gates + (size_t)(m - 1) * NROW;
                float gi = gp[t], gf = gp[HID + t], gg = gp[2 * HID + t], go = gp[3 * HID + t];
                c = sigf(gf) * c + sigf(gi) * tanhf_fast(gg);
                h = sigf(go) * tanhf_fast(c);
            }
            __syncthreads();
            hsh[t] = h;
            __syncthreads();
            const f32x4* p4 = (const f32x4*)hsh;
            float acc = 0.f;
            #pragma unroll
            for (int kk = 0; kk < 16; ++kk) acc += dot4(w4[q * 16 + kk], p4[q * 16 + kk]);
            acc += __shfl_xor(acc, 1);
            acc += __shfl_xor(acc, 2);
            if (q == 0) tab[(which * KSTEPS + m) * ZM + j] = acc + bj;
            __threadfence();                     // publish tab row before flag
            __syncthreads();
            if (t == 0)
                __hip_atomic_store(&flags[which * KSTEPS + m], 1u,
                                   __ATOMIC_RELEASE, __HIP_MEMORY_SCOPE_AGENT);
        }
    }

    // ================= broadcast phase (ALL 1792 blocks) =================
    const int wm = b >> 7, chunk = b & 127;
    if (t == 0) {
        while (__hip_atomic_load(&flags[wm], __ATOMIC_ACQUIRE, __HIP_MEMORY_SCOPE_AGENT) == 0u)
            __builtin_amdgcn_s_sleep(2);
    }
    __syncthreads();
    const f32x4 v = ((const f32x4*)tab)[wm * 16 + (t & 15)];
    size_t base = (size_t)wm * (WMSZ / 4) + (size_t)chunk * 4096 + t;
    #pragma unroll
    for (int k = 0; k < 16; ++k)
        __builtin_nontemporal_store(v, &out[base + (size_t)k * 256]);
}

extern "C" void kernel_launch(void* const* d_in, const int* in_sizes, int n_in,
                              void* d_out, int out_size, void* d_ws, size_t ws_size,
                              hipStream_t stream) {
    const float* zm1  = (const float*)d_in[0];
    const float* Wih  = (const float*)d_in[1];
    const float* Whh  = (const float*)d_in[2];
    const float* bih  = (const float*)d_in[3];
    const float* bhh  = (const float*)d_in[4];
    const float* Wloc = (const float*)d_in[5];
    const float* bloc = (const float*)d_in[6];
    const float* Wsc  = (const float*)d_in[7];
    const float* bsc  = (const float*)d_in[8];
    float* ws  = (float*)d_ws;
    f32x4* out = (f32x4*)d_out;

    // zero flags + counters (ws is poisoned 0xAA before every launch)
    (void)hipMemsetAsync(d_ws, 0, 256, stream);

    mega_kernel<<<NBLKS, 256, 0, stream>>>(zm1, Wih, Whh, bih, bhh,
                                           Wloc, bloc, Wsc, bsc, ws, out);
}

// Round 10
// 231.547 us; speedup vs baseline: 4.3997x; 4.3997x over previous
//
#include <hip/hip_runtime.h>
#include <cstdint>
#include <cstddef>

#define HID    256
#define NROW   1024          // 4*HID gate rows
#define KSTEPS 7
#define ZM     64
#define BATCH  32768
#define WMSZ   (BATCH * ZM)  // floats per (which,m) output slab
#define NBLKS  1792          // 14 slabs x 128 chunks; 66 lowest blocks double as producers

typedef float f32x4 __attribute__((ext_vector_type(4)));

// ---- ws layout. uints [0, 29696) zeroed by hipMemsetAsync (118,784 B):
//   gcnt[s]  at uint index s*64            (6 counters, 256 B apart)
//   flag[b]  at uint index 1024 + b*16     (1792 per-consumer-block flags, 64 B apart)
// floats after that:
#define WSU_GCNT(s)  ((s) * 64)
#define WSU_FLAG(b)  (1024 + (b) * 16)
#define MEMSET_BYTES 118784
#define WS_GATES 29696                  // 6 x 1024 pre-activation gates
#define WS_TAB   (29696 + 6 * NROW)     // 896 projection table [which][m][j]

__device__ __forceinline__ float sigf(float x)       { return 1.0f / (1.0f + __expf(-x)); }
__device__ __forceinline__ float tanhf_fast(float x) { return 1.0f - 2.0f / (__expf(2.0f * x) + 1.0f); }
__device__ __forceinline__ float dot4(f32x4 a, f32x4 b) {
    return a.x * b.x + a.y * b.y + a.z * b.z + a.w * b.w;
}

__global__ __launch_bounds__(256, 8) void mega_kernel(
    const float* __restrict__ zm1,
    const float* __restrict__ Wih, const float* __restrict__ Whh,
    const float* __restrict__ bih, const float* __restrict__ bhh,
    const float* __restrict__ Wloc, const float* __restrict__ bloc,
    const float* __restrict__ Wsc,  const float* __restrict__ bsc,
    float* __restrict__ ws, f32x4* __restrict__ out)
{
    const int t = threadIdx.x, b = blockIdx.x;
    unsigned* wsu  = (unsigned*)ws;
    float* gates = ws + WS_GATES;
    float* tab   = ws + WS_TAB;

    __shared__ float hsh[HID];

    // ================= producer phase (blocks 0..65 only) =================
    if (b < 64) {
        // ---- gate-matvec producer: 16 rows, 16 threads/row, 16 cols/thread ----
        float c = 0.f;                           // c[t] chain, redundant per block
        const int row = b * 16 + (t >> 4);
        const int cb  = (t & 15) * 4;            // f32x4 column base
        const f32x4* wi = (const f32x4*)(Wih + (size_t)row * HID);
        const f32x4* wh = (const f32x4*)(Whh + (size_t)row * HID);
        const float bias = bih[row] + bhh[row];
        #pragma unroll 1
        for (int s = 0; s <= 5; ++s) {
            float h;
            if (s == 0) {
                h = zm1[t];                      // h0==0: step 0 uses Wih.zm1 only
            } else {
                if (t == 0) {
                    unsigned* g = &wsu[WSU_GCNT(s - 1)];
                    while (__hip_atomic_load(g, __ATOMIC_RELAXED, __HIP_MEMORY_SCOPE_AGENT) < 64u)
                        __builtin_amdgcn_s_sleep(1);
                    (void)__hip_atomic_load(g, __ATOMIC_ACQUIRE, __HIP_MEMORY_SCOPE_AGENT);
                }
                __syncthreads();
                const float* gp = gates + (size_t)(s - 1) * NROW;
                float gi = gp[t], gf = gp[HID + t], gg = gp[2 * HID + t], go = gp[3 * HID + t];
                c = sigf(gf) * c + sigf(gi) * tanhf_fast(gg);
                h = sigf(go) * tanhf_fast(c);
            }
            __syncthreads();
            hsh[t] = h;
            __syncthreads();
            const f32x4* h4 = (const f32x4*)hsh;
            float part = 0.f;
            #pragma unroll
            for (int kk = 0; kk < 4; ++kk) {
                f32x4 hv = h4[cb + kk];
                part += dot4(wi[cb + kk], hv);
                if (s > 0) part += dot4(wh[cb + kk], hv);
            }
            part += __shfl_xor(part, 1);
            part += __shfl_xor(part, 2);
            part += __shfl_xor(part, 4);
            part += __shfl_xor(part, 8);
            if ((t & 15) == 0) gates[(size_t)s * NROW + row] = part + bias;
            __threadfence();                     // publish gates before count bump
            __syncthreads();
            if (t == 0)
                __hip_atomic_fetch_add(&wsu[WSU_GCNT(s)], 1u,
                                       __ATOMIC_RELEASE, __HIP_MEMORY_SCOPE_AGENT);
        }
    } else if (b < 66) {
        // ---- projection producer: b=64 -> loc, b=65 -> scale ----
        float c = 0.f;
        const int which = b - 64;
        const float* W  = which ? Wsc : Wloc;
        const float* bv = which ? bsc : bloc;
        const int j = t >> 2, q = t & 3;
        const f32x4* w4 = (const f32x4*)(W + (size_t)j * HID);
        const float bj = bv[j];
        #pragma unroll 1
        for (int m = 0; m <= 6; ++m) {
            float h;
            if (m == 0) {
                h = zm1[t];
            } else {
                if (t == 0) {
                    unsigned* g = &wsu[WSU_GCNT(m - 1)];
                    while (__hip_atomic_load(g, __ATOMIC_RELAXED, __HIP_MEMORY_SCOPE_AGENT) < 64u)
                        __builtin_amdgcn_s_sleep(1);
                    (void)__hip_atomic_load(g, __ATOMIC_ACQUIRE, __HIP_MEMORY_SCOPE_AGENT);
                }
                __syncthreads();
                const float* gp = gates + (size_t)(m - 1) * NROW;
                float gi = gp[t], gf = gp[HID + t], gg = gp[2 * HID + t], go = gp[3 * HID + t];
                c = sigf(gf) * c + sigf(gi) * tanhf_fast(gg);
                h = sigf(go) * tanhf_fast(c);
            }
            __syncthreads();
            hsh[t] = h;
            __syncthreads();
            const f32x4* p4 = (const f32x4*)hsh;
            float acc = 0.f;
            #pragma unroll
            for (int kk = 0; kk < 16; ++kk) acc += dot4(w4[q * 16 + kk], p4[q * 16 + kk]);
            acc += __shfl_xor(acc, 1);
            acc += __shfl_xor(acc, 2);
            const int wm = which * KSTEPS + m;
            if (q == 0) tab[wm * ZM + j] = acc + bj;
            __threadfence();                     // publish tab row before flags
            __syncthreads();
            // fan-out: one private flag per consumer block of this slab (disjoint lines)
            if (t < 128)
                __hip_atomic_store(&wsu[WSU_FLAG(wm * 128 + t)], 1u,
                                   __ATOMIC_RELEASE, __HIP_MEMORY_SCOPE_AGENT);
        }
    }

    // ================= broadcast phase (ALL 1792 blocks) =================
    const int wm = b >> 7, chunk = b & 127;
    if (t == 0) {
        unsigned* f = &wsu[WSU_FLAG(b)];
        while (__hip_atomic_load(f, __ATOMIC_RELAXED, __HIP_MEMORY_SCOPE_AGENT) == 0u)
            __builtin_amdgcn_s_sleep(64);
        (void)__hip_atomic_load(f, __ATOMIC_ACQUIRE, __HIP_MEMORY_SCOPE_AGENT);
    }
    __syncthreads();
    const f32x4 v = ((const f32x4*)tab)[wm * 16 + (t & 15)];
    size_t base = (size_t)wm * (WMSZ / 4) + (size_t)chunk * 4096 + t;
    #pragma unroll
    for (int k = 0; k < 16; ++k)
        __builtin_nontemporal_store(v, &out[base + (size_t)k * 256]);
}

extern "C" void kernel_launch(void* const* d_in, const int* in_sizes, int n_in,
                              void* d_out, int out_size, void* d_ws, size_t ws_size,
                              hipStream_t stream) {
    const float* zm1  = (const float*)d_in[0];
    const float* Wih  = (const float*)d_in[1];
    const float* Whh  = (const float*)d_in[2];
    const float* bih  = (const float*)d_in[3];
    const float* bhh  = (const float*)d_in[4];
    const float* Wloc = (const float*)d_in[5];
    const float* bloc = (const float*)d_in[6];
    const float* Wsc  = (const float*)d_in[7];
    const float* bsc  = (const float*)d_in[8];
    float* ws  = (float*)d_ws;
    f32x4* out = (f32x4*)d_out;

    // zero sync region (ws is poisoned 0xAA before every launch)
    (void)hipMemsetAsync(d_ws, 0, MEMSET_BYTES, stream);

    mega_kernel<<<NBLKS, 256, 0, stream>>>(zm1, Wih, Whh, bih, bhh,
                                           Wloc, bloc, Wsc, bsc, ws, out);
}